// Round 8
// baseline (88.803 us; speedup 1.0000x reference)
//
#include <hip/hip_runtime.h>
#include <math.h>

#define NB 4
#define NL 256
#define NP 32

// HD^-0.5 * log2(e) folded into W2Q/BQ2; bias pre-multiplied by log2(e).
static constexpr float SCALE = 0.17677669529663687f * 1.4426950408889634f;
static constexpr float LOG2E = 1.4426950408889634f;

typedef __bf16 bf16x8 __attribute__((ext_vector_type(8)));
typedef float f32x4 __attribute__((ext_vector_type(4)));
typedef float f32x16 __attribute__((ext_vector_type(16)));
typedef unsigned int u32x4 __attribute__((ext_vector_type(4)));
typedef unsigned int u32x2 __attribute__((ext_vector_type(2)));

// ---- ws byte offsets (total ~1.5 MB) ----
#define WS_W2QT 0                        // [256 j][128 c] bf16 = 65536
#define WS_BQ2  65536                    // 256 f32 = 1024
#define WS_WKT  66560                    // [256 j][256 k] bf16 = 131072
#define WS_WVT  (66560 + 131072)
#define WS_WOT  (66560 + 2 * 131072)
#define WS_KIMG (66560 + 3 * 131072)     // per (b,h): [256 key][32 d] bf16 = 16384; x32
#define WS_VT   (WS_KIMG + 524288)       // per (b,h): [32 d][256 key] bf16 = 16384; x32

__device__ __forceinline__ unsigned short bf16b(float x) {
  return __builtin_bit_cast(unsigned short, (__bf16)x);
}
__device__ __forceinline__ unsigned pack2(float a, float b) {
  return (unsigned)bf16b(a) | ((unsigned)bf16b(b) << 16);
}
// v_permlane32_swap_b32: a' = {a.lo, b.lo}, b' = {a.hi, b.hi}
__device__ __forceinline__ void pl32swap(unsigned& a, unsigned& b) {
  asm("v_permlane32_swap_b32 %0, %1" : "+v"(a), "+v"(b));
}
// XOR-swizzled byte offset of (row, 16B-chunk) in per-ktblock [N][32]bf16 tiles.
__device__ __forceinline__ int fqs(int row, int chunk, int ktb, int ktbytes) {
  int slot = (((row & 1) << 2) + chunk) ^ ((row >> 1) & 7) ^ (ktb & 7);
  return ktb * ktbytes + (row >> 1) * 128 + slot * 16;
}
__device__ __forceinline__ f32x4 zero4() { return (f32x4){0.f, 0.f, 0.f, 0.f}; }

// ---------------------------------------------------------------------------
// prep: W2QT bf16 (scale+log2e folded), BQ2 f32, and bf16 transposed images
// of wk/wv/wo.  grid = 225 blocks x 256.
// ---------------------------------------------------------------------------
__global__ __launch_bounds__(256) void prep_kernel(
    const float* __restrict__ w2, const float* __restrict__ b2,
    const float* __restrict__ wq, const float* __restrict__ bq,
    const float* __restrict__ wk, const float* __restrict__ wv,
    const float* __restrict__ wo, char* __restrict__ ws) {
  int c = blockIdx.x, j = threadIdx.x;
  if (c < 128) {
    __shared__ float row[256];
    row[j] = w2[c * 256 + j];
    __syncthreads();
    float acc = 0.f;
#pragma unroll 8
    for (int e = 0; e < 256; ++e) acc = fmaf(row[e], wq[e * 256 + j], acc);
    *(unsigned short*)(ws + WS_W2QT + j * 256 + c * 2) = bf16b(acc * SCALE);
  } else if (c == 128) {
    float acc = bq[j];
    for (int e = 0; e < 256; ++e) acc = fmaf(b2[e], wq[e * 256 + j], acc);
    ((float*)(ws + WS_BQ2))[j] = acc * SCALE;
  } else {
    int idx = c - 129;  // 0..95
    const float* src = (idx < 32) ? wk : (idx < 64) ? wv : wo;
    char* dst = ws + WS_WKT + (size_t)(idx >> 5) * 131072;
    int kblk = idx & 31;
    __shared__ float tl[8][257];
#pragma unroll
    for (int r = 0; r < 8; ++r) tl[r][j] = src[(kblk * 8 + r) * 256 + j];
    __syncthreads();
    u32x4 v;
#pragma unroll
    for (int r2 = 0; r2 < 4; ++r2)
      v[r2] = pack2(tl[2 * r2][j], tl[2 * r2 + 1][j]);
    *(u32x4*)(dst + j * 512 + kblk * 16) = v;
  }
}

// ---------------------------------------------------------------------------
// kv: MFMA projections. 64 blocks x 16 ehr rows. Emits KIMG [key][32d] and
// VT [32d][key] bf16 images per (b,h).
// ---------------------------------------------------------------------------
__global__ __launch_bounds__(256) void kv_kernel(
    const float* __restrict__ ehr, const float* __restrict__ bk,
    const float* __restrict__ bv, char* __restrict__ ws) {
  __shared__ __align__(16) char Alds[8192];
  int t = threadIdx.x;
  int R0 = blockIdx.x * 16;
  {
    int row = t >> 4;
#pragma unroll
    for (int u = 0; u < 2; ++u) {
      int c = (t & 15) * 2 + u;  // 16B chunk 0..31
      const float4* s4 = (const float4*)(ehr + (size_t)(R0 + row) * 256 + c * 8);
      float4 x0 = s4[0], x1 = s4[1];
      bf16x8 pk;
      pk[0] = (__bf16)x0.x; pk[1] = (__bf16)x0.y; pk[2] = (__bf16)x0.z; pk[3] = (__bf16)x0.w;
      pk[4] = (__bf16)x1.x; pk[5] = (__bf16)x1.y; pk[6] = (__bf16)x1.z; pk[7] = (__bf16)x1.w;
      *(bf16x8*)(Alds + fqs(row, c & 3, c >> 2, 1024)) = pk;
    }
  }
  __syncthreads();
  int lane = t & 63, w = t >> 6, lo = lane & 15, hi = lane >> 4;
  f32x4 aK[4], aV[4];
#pragma unroll
  for (int nt = 0; nt < 4; ++nt) { aK[nt] = zero4(); aV[nt] = zero4(); }
  const char* wkT = ws + WS_WKT;
  const char* wvT = ws + WS_WVT;
#pragma unroll
  for (int kt = 0; kt < 8; ++kt) {
    bf16x8 af = *(const bf16x8*)(Alds + fqs(lo, hi, kt, 1024));
#pragma unroll
    for (int nt = 0; nt < 4; ++nt) {
      int j = (w * 4 + nt) * 16 + lo;
      bf16x8 bK = *(const bf16x8*)(wkT + j * 512 + (kt * 32 + hi * 8) * 2);
      bf16x8 bV = *(const bf16x8*)(wvT + j * 512 + (kt * 32 + hi * 8) * 2);
      aK[nt] = __builtin_amdgcn_mfma_f32_16x16x32_bf16(af, bK, aK[nt], 0, 0, 0);
      aV[nt] = __builtin_amdgcn_mfma_f32_16x16x32_bf16(af, bV, aV[nt], 0, 0, 0);
    }
  }
  int b = R0 >> 8;
  int l0 = (R0 & 255) + hi * 4;
#pragma unroll
  for (int nt = 0; nt < 4; ++nt) {
    int j = (w * 4 + nt) * 16 + lo;
    int h = j >> 5, d = j & 31;
    float bkj = bk[j], bvj = bv[j];
    char* kb = ws + WS_KIMG + (size_t)(b * 8 + h) * 16384;
#pragma unroll
    for (int i = 0; i < 4; ++i)
      *(unsigned short*)(kb + (l0 + i) * 64 + d * 2) = bf16b(aK[nt][i] + bkj);
    u32x2 vv;
    vv[0] = pack2(aV[nt][0] + bvj, aV[nt][1] + bvj);
    vv[1] = pack2(aV[nt][2] + bvj, aV[nt][3] + bvj);
    *(u32x2*)(ws + WS_VT + (size_t)(b * 8 + h) * 16384 + d * 512 + l0 * 2) = vv;
  }
}

// ---------------------------------------------------------------------------
// attn v8 (diagnostic): block=(b,p,32-row eighth), 512 thr, wave=head.
// Identical to v7 up through the flash loop; epilogue writes ctx bf16 into
// out-row upper halves (v5's byte-exact formula). Separate oproj finishes.
// ---------------------------------------------------------------------------
__global__ __launch_bounds__(512, 8) void attn_kernel(
    const float* __restrict__ ehr_times, const float* __restrict__ itv,
    const float* __restrict__ w1, const float* __restrict__ b1,
    const char* __restrict__ ws, float* __restrict__ outp) {
  __shared__ __align__(16) char Hlds[8192];    // [32 row][128 c] bf16, 16B-chunk ^row swz
  __shared__ __align__(16) float bias_s[256];
  __shared__ __align__(16) float w1i[512];
  int t = threadIdx.x;
  int bid = blockIdx.x;  // (b*32+p)*8 + lq
  int b = bid >> 8, p = (bid >> 3) & 31, lq = bid & 7;
  {
    int cc = t >> 2, r = t & 3;
    w1i[t] = (r < 3) ? w1[r * 128 + cc] : b1[cc];
  }
  float st = itv[(b * NP + p) * 2 + 0];
  float en = itv[(b * NP + p) * 2 + 1];
  if (t < 256) {
    float tk = ehr_times[b * 256 + t];
    bool valid = (tk >= st) && (tk <= en);
    bias_s[t] = valid ? -fabsf(tk - 0.5f * (st + en)) * LOG2E : -1.0e30f;
  }
  __syncthreads();
  {  // H = gelu(tf @ w1 + b1) for this block's 32 rows; 8 gelu/thread
    int row = t >> 4;
    int cz = t & 15;  // 16B chunk, c = cz*8..+7
    float tl = ehr_times[b * 256 + lq * 32 + row];
    float dsv = tl - st, dev = en - tl;
    float sg = 1.f / (1.f + __expf(-dsv * dev));
    const float4* w14 = (const float4*)w1i;
    bf16x8 pk;
#pragma unroll
    for (int u = 0; u < 8; ++u) {
      float4 wv = w14[cz * 8 + u];
      float x = fmaf(dsv, wv.x, fmaf(dev, wv.y, fmaf(sg, wv.z, wv.w)));
      pk[u] = (__bf16)(0.5f * x * (1.f + erff(x * 0.70710678118654752f)));
    }
    *(bf16x8*)(Hlds + row * 256 + ((cz ^ (row & 15)) << 4)) = pk;
  }
  __syncthreads();

  int lane = t & 63, h = t >> 6;
  int cl = lane & 31;  // col within 32-tile
  int hb = lane >> 5;  // half

  // ---- q-build: q^T = W2QT_h @ H^T (+BQ2 via C-init) ----
  u32x4 qbA, qbB;
  {
    const float* BQ2 = (const float*)(ws + WS_BQ2);
    f32x16 s;
#pragma unroll
    for (int g = 0; g < 4; ++g) {
      f32x4 v = *(const f32x4*)(BQ2 + h * 32 + g * 8 + hb * 4);
      s[4 * g + 0] = v[0]; s[4 * g + 1] = v[1];
      s[4 * g + 2] = v[2]; s[4 * g + 3] = v[3];
    }
    const char* WQ = ws + WS_W2QT + (size_t)(h * 32 + cl) * 256 + hb * 16;
#pragma unroll
    for (int ck = 0; ck < 8; ++ck) {
      bf16x8 aW = *(const bf16x8*)(WQ + ck * 32);
      bf16x8 bh = *(const bf16x8*)(Hlds + cl * 256 +
                                   ((((ck << 1) | hb) ^ (cl & 15)) << 4));
      s = __builtin_amdgcn_mfma_f32_32x32x16_bf16(aW, bh, s, 0, 0, 0);
    }
    unsigned u0 = pack2(s[0], s[1]), u1 = pack2(s[2], s[3]);
    unsigned u2 = pack2(s[4], s[5]), u3 = pack2(s[6], s[7]);
    unsigned u4 = pack2(s[8], s[9]), u5 = pack2(s[10], s[11]);
    unsigned u6 = pack2(s[12], s[13]), u7 = pack2(s[14], s[15]);
    pl32swap(u0, u2); pl32swap(u1, u3); pl32swap(u4, u6); pl32swap(u5, u7);
    qbA[0] = u0; qbA[1] = u1; qbA[2] = u2; qbA[3] = u3;
    qbB[0] = u4; qbB[1] = u5; qbB[2] = u6; qbB[3] = u7;
  }

  // ---- flash loop: 8 key-blocks of 32; no LDS writes, no barriers ----
  f32x16 acc0;
#pragma unroll
  for (int i = 0; i < 16; ++i) acc0[i] = 0.f;
  float z0 = 0.f;
  const char* Kb = ws + WS_KIMG + (size_t)(b * 8 + h) * 16384;
  const char* Vb = ws + WS_VT + (size_t)(b * 8 + h) * 16384;
#pragma unroll 2
  for (int kb = 0; kb < 8; ++kb) {
    const char* kp = Kb + (kb * 32 + cl) * 64 + hb * 16;
    bf16x8 kf0 = *(const bf16x8*)kp;
    bf16x8 kf1 = *(const bf16x8*)(kp + 32);
    const char* vp = Vb + cl * 512 + kb * 64 + hb * 16;
    bf16x8 vf0 = *(const bf16x8*)vp;
    bf16x8 vf1 = *(const bf16x8*)(vp + 32);
    f32x16 s;
    {
      f32x4 b0 = *(const f32x4*)(bias_s + kb * 32 + hb * 4);
      f32x4 b1v = *(const f32x4*)(bias_s + kb * 32 + 8 + hb * 4);
      f32x4 b2v = *(const f32x4*)(bias_s + kb * 32 + 16 + hb * 4);
      f32x4 b3v = *(const f32x4*)(bias_s + kb * 32 + 24 + hb * 4);
      s[0] = b0[0]; s[1] = b0[1]; s[2] = b0[2]; s[3] = b0[3];
      s[4] = b1v[0]; s[5] = b1v[1]; s[6] = b1v[2]; s[7] = b1v[3];
      s[8] = b2v[0]; s[9] = b2v[1]; s[10] = b2v[2]; s[11] = b2v[3];
      s[12] = b3v[0]; s[13] = b3v[1]; s[14] = b3v[2]; s[15] = b3v[3];
    }
    s = __builtin_amdgcn_mfma_f32_32x32x16_bf16(kf0, __builtin_bit_cast(bf16x8, qbA), s, 0, 0, 0);
    s = __builtin_amdgcn_mfma_f32_32x32x16_bf16(kf1, __builtin_bit_cast(bf16x8, qbB), s, 0, 0, 0);
    float e[16];
#pragma unroll
    for (int i = 0; i < 16; ++i) e[i] = exp2f(s[i]);
#pragma unroll
    for (int i = 0; i < 16; ++i) z0 += e[i];
    unsigned u0 = pack2(e[0], e[1]), u1 = pack2(e[2], e[3]);
    unsigned u2 = pack2(e[4], e[5]), u3 = pack2(e[6], e[7]);
    unsigned u4 = pack2(e[8], e[9]), u5 = pack2(e[10], e[11]);
    unsigned u6 = pack2(e[12], e[13]), u7 = pack2(e[14], e[15]);
    pl32swap(u0, u2); pl32swap(u1, u3); pl32swap(u4, u6); pl32swap(u5, u7);
    u32x4 plo, phi;
    plo[0] = u0; plo[1] = u1; plo[2] = u2; plo[3] = u3;
    phi[0] = u4; phi[1] = u5; phi[2] = u6; phi[3] = u7;
    acc0 = __builtin_amdgcn_mfma_f32_32x32x16_bf16(vf0, __builtin_bit_cast(bf16x8, plo), acc0, 0, 0, 0);
    acc0 = __builtin_amdgcn_mfma_f32_32x32x16_bf16(vf1, __builtin_bit_cast(bf16x8, phi), acc0, 0, 0, 0);
  }

  // ---- Z cross-half reduce; ctx bf16 -> out-row upper halves (v5 formula)
  z0 += __shfl_xor(z0, 32);
  float rz = 1.f / z0;
  {
    size_t rowbase = (size_t)(b * NP + p) * 256 + lq * 32;
    char* po = (char*)outp + (rowbase + cl) * 1024 + 512 + h * 64 + hb * 8;
#pragma unroll
    for (int g = 0; g < 4; ++g) {
      u32x2 o;
      o[0] = pack2(acc0[4 * g + 0] * rz, acc0[4 * g + 1] * rz);
      o[1] = pack2(acc0[4 * g + 2] * rz, acc0[4 * g + 3] * rz);
      *(u32x2*)(po + g * 16) = o;  // d = h*32 + g*8 + 4*hb + i
    }
  }
}

// ---------------------------------------------------------------------------
// oproj (verbatim round-5, verified): MFMA, in-place per 64-row block.
// ---------------------------------------------------------------------------
__global__ __launch_bounds__(256) void oproj_kernel(
    const float* __restrict__ bo, const char* __restrict__ ws,
    float* __restrict__ outp) {
  __shared__ __align__(16) char Alds[32768];
  int t = threadIdx.x;
  int r0 = blockIdx.x * 64;
  {
    int row = t >> 2;
    const char* src = (const char*)outp + (size_t)(r0 + row) * 1024 + 512 + (t & 3) * 128;
#pragma unroll
    for (int u = 0; u < 8; ++u) {
      int c = (t & 3) * 8 + u;
      u32x4 v = *(const u32x4*)(src + u * 16);
      *(u32x4*)(Alds + fqs(row, c & 3, c >> 2, 4096)) = v;
    }
  }
  __syncthreads();
  int lane = t & 63, w = t >> 6, lo = lane & 15, hi = lane >> 4;
  f32x4 acc[4][4];
#pragma unroll
  for (int rt = 0; rt < 4; ++rt)
#pragma unroll
    for (int nt = 0; nt < 4; ++nt) acc[rt][nt] = zero4();
  const char* woT = ws + WS_WOT;
#pragma unroll
  for (int kt = 0; kt < 8; ++kt) {
    bf16x8 af[4];
#pragma unroll
    for (int rt = 0; rt < 4; ++rt)
      af[rt] = *(const bf16x8*)(Alds + fqs(rt * 16 + lo, hi, kt, 4096));
#pragma unroll
    for (int nt = 0; nt < 4; ++nt) {
      int j = (w * 4 + nt) * 16 + lo;
      bf16x8 bf = *(const bf16x8*)(woT + j * 512 + (kt * 32 + hi * 8) * 2);
#pragma unroll
      for (int rt = 0; rt < 4; ++rt)
        acc[rt][nt] = __builtin_amdgcn_mfma_f32_16x16x32_bf16(af[rt], bf, acc[rt][nt], 0, 0, 0);
    }
  }
#pragma unroll
  for (int nt = 0; nt < 4; ++nt) {
    int j = (w * 4 + nt) * 16 + lo;
    float boj = bo[j];
#pragma unroll
    for (int rt = 0; rt < 4; ++rt)
#pragma unroll
      for (int i = 0; i < 4; ++i)
        outp[(size_t)(r0 + rt * 16 + hi * 4 + i) * 256 + j] = acc[rt][nt][i] + boj;
  }
}

// ---------------------------------------------------------------------------
extern "C" void kernel_launch(void* const* d_in, const int* in_sizes, int n_in,
                              void* d_out, int out_size, void* d_ws, size_t ws_size,
                              hipStream_t stream) {
  const float* ehr = (const float*)d_in[0];
  const float* ehr_times = (const float*)d_in[1];
  const float* itv = (const float*)d_in[2];
  const float* w1 = (const float*)d_in[3];
  const float* b1 = (const float*)d_in[4];
  const float* w2 = (const float*)d_in[5];
  const float* b2 = (const float*)d_in[6];
  const float* wq = (const float*)d_in[7];
  const float* bq = (const float*)d_in[8];
  const float* wk = (const float*)d_in[9];
  const float* bk = (const float*)d_in[10];
  const float* wv = (const float*)d_in[11];
  const float* bv = (const float*)d_in[12];
  const float* wo = (const float*)d_in[13];
  const float* bo = (const float*)d_in[14];
  float* out = (float*)d_out;
  char* ws = (char*)d_ws;

  prep_kernel<<<225, 256, 0, stream>>>(w2, b2, wq, bq, wk, wv, wo, ws);
  kv_kernel<<<64, 256, 0, stream>>>(ehr, bk, bv, ws);
  attn_kernel<<<NB * NP * 8, 512, 0, stream>>>(ehr_times, itv, w1, b1, ws, out);
  oproj_kernel<<<(NB * NP * NL) / 64, 256, 0, stream>>>(bo, ws, out);
}